// Round 13
// baseline (76.812 us; speedup 1.0000x reference)
//
#include <hip/hip_runtime.h>
#include <math.h>

#define THREADS 256
#define NWAVE 4
#define QB 256           // queries per block (4 per lane)
#define TILE 512         // targets per LDS tile (8 KB)
#define KSPLIT 8         // knn target split factor
#define CSPLIT 4         // chamfer target split factor

#define MED3 __builtin_amdgcn_fmed3f

// branchless sorted insert via med3: 5 independent ops, no serial chain.
#define INS5(L0,L1,L2,L3,L4,C) do { float c_=(C);              \
    float n0_=fminf(L0,c_);                                    \
    float n1_=MED3(L0,L1,c_);                                  \
    float n2_=MED3(L1,L2,c_);                                  \
    float n3_=MED3(L2,L3,c_);                                  \
    float n4_=MED3(L3,L4,c_);                                  \
    L0=n0_; L1=n1_; L2=n2_; L3=n3_; L4=n4_; } while (0)

// tile stores (-2x, -2y, -2z, |t|^2): dist-na = 3 fma
__device__ __forceinline__ float cdist(float qx,float qy,float qz,float4 t) {
    return fmaf(qx, t.x, fmaf(qy, t.y, fmaf(qz, t.z, t.w)));
}

// blocks [0, knnItems): role 2 (knn), targets split KSPLIT ways -> knnPart
// blocks [knnItems,...): roles 0/1 (chamfer), targets split CSPLIT ways -> chamPart
__global__ __launch_bounds__(THREADS) void scan_kernel(
    const float* __restrict__ pred, const float* __restrict__ gt,
    float* __restrict__ chamPart, float* __restrict__ knnPart,
    int B, int N, int chunks, int knnItems)
{
    // LDS union: tile (512 float4 = 2048 floats) overlays part
    // (NWAVE*QB*5 = 5120 floats). tile is dead after the loop's final barrier.
    __shared__ float shbuf[NWAVE * QB * 5];
    float4* tile = reinterpret_cast<float4*>(shbuf);
#define PART(ww,t,k) shbuf[(((ww) * QB) + (t)) * 5 + (k)]

    const float FLT_INF = 3.4e38f;
    int w = threadIdx.x >> 6, l = threadIdx.x & 63;

    int role, b, chunk, split, tBegin, tEnd;
    if ((int)blockIdx.x < knnItems) {
        role = 2;
        int u = blockIdx.x;
        split = u % KSPLIT; u /= KSPLIT;
        chunk = u % chunks; b = u / chunks;
        int seg = (N + KSPLIT - 1) / KSPLIT;
        tBegin = split * seg; tEnd = min(tBegin + seg, N);
    } else {
        int u = blockIdx.x - knnItems;
        int perRole = B * chunks * CSPLIT;
        role = u / perRole; u %= perRole;
        split = u % CSPLIT; u /= CSPLIT;
        chunk = u % chunks; b = u / chunks;
        int seg = (N + CSPLIT - 1) / CSPLIT;
        tBegin = split * seg; tEnd = min(tBegin + seg, N);
    }

    const float* qb = (((role == 0) ? gt : pred)) + (size_t)b * N * 3;
    const float* tb = (((role == 1) ? gt : pred)) + (size_t)b * N * 3;

    // 4 queries per lane, slots s*64 + l
    int qiA = chunk * QB +   0 + l;
    int qiB = chunk * QB +  64 + l;
    int qiC = chunk * QB + 128 + l;
    int qiD = chunk * QB + 192 + l;

    float ax=0.f,ay=0.f,az=0.f, bx=0.f,by=0.f,bz=0.f;
    float cx=0.f,cy=0.f,cz=0.f, dx=0.f,dy=0.f,dz=0.f;
    if (qiA < N) { ax=qb[qiA*3]; ay=qb[qiA*3+1]; az=qb[qiA*3+2]; }
    if (qiB < N) { bx=qb[qiB*3]; by=qb[qiB*3+1]; bz=qb[qiB*3+2]; }
    if (qiC < N) { cx=qb[qiC*3]; cy=qb[qiC*3+1]; cz=qb[qiC*3+2]; }
    if (qiD < N) { dx=qb[qiD*3]; dy=qb[qiD*3+1]; dz=qb[qiD*3+2]; }

    // chamfer mins (1 chain per query)
    float mA = FLT_INF, mB = FLT_INF, mC = FLT_INF, mD = FLT_INF;
    // knn top-5 lists per query
    float a0=FLT_INF,a1=FLT_INF,a2=FLT_INF,a3=FLT_INF,a4=FLT_INF;
    float b0=FLT_INF,b1=FLT_INF,b2=FLT_INF,b3=FLT_INF,b4=FLT_INF;
    float c0=FLT_INF,c1=FLT_INF,c2=FLT_INF,c3=FLT_INF,c4=FLT_INF;
    float d0=FLT_INF,d1=FLT_INF,d2=FLT_INF,d3=FLT_INF,d4=FLT_INF;

    for (int t0 = tBegin; t0 < tEnd; t0 += TILE) {
        int cnt = min(TILE, tEnd - t0);
        for (int k = threadIdx.x; k < cnt; k += THREADS) {
            float x = tb[(size_t)(t0 + k) * 3 + 0];
            float y = tb[(size_t)(t0 + k) * 3 + 1];
            float z = tb[(size_t)(t0 + k) * 3 + 2];
            tile[k] = make_float4(-2.f*x, -2.f*y, -2.f*z, fmaf(x,x,fmaf(y,y,z*z)));
        }
        __syncthreads();

        int seg = (cnt + NWAVE - 1) / NWAVE;
        int jb = w * seg, je = min(jb + seg, cnt);

        if (role < 2) {
            int j = jb;
            for (; j + 2 <= je; j += 2) {
                float4 t0v = tile[j], t1v = tile[j+1];
                mA = fminf(mA, cdist(ax,ay,az,t0v));
                mB = fminf(mB, cdist(bx,by,bz,t0v));
                mC = fminf(mC, cdist(cx,cy,cz,t0v));
                mD = fminf(mD, cdist(dx,dy,dz,t0v));
                mA = fminf(mA, cdist(ax,ay,az,t1v));
                mB = fminf(mB, cdist(bx,by,bz,t1v));
                mC = fminf(mC, cdist(cx,cy,cz,t1v));
                mD = fminf(mD, cdist(dx,dy,dz,t1v));
            }
            if (j < je) {
                float4 t = tile[j];
                mA = fminf(mA, cdist(ax,ay,az,t));
                mB = fminf(mB, cdist(bx,by,bz,t));
                mC = fminf(mC, cdist(cx,cy,cz,t));
                mD = fminf(mD, cdist(dx,dy,dz,t));
            }
        } else {
            int j = jb;
            for (; j + 2 <= je; j += 2) {
                float4 t0v = tile[j], t1v = tile[j+1];
                float cA0 = cdist(ax,ay,az,t0v), cA1 = cdist(ax,ay,az,t1v);
                float cB0 = cdist(bx,by,bz,t0v), cB1 = cdist(bx,by,bz,t1v);
                float cC0 = cdist(cx,cy,cz,t0v), cC1 = cdist(cx,cy,cz,t1v);
                float cD0 = cdist(dx,dy,dz,t0v), cD1 = cdist(dx,dy,dz,t1v);
                INS5(a0,a1,a2,a3,a4, cA0); INS5(a0,a1,a2,a3,a4, cA1);
                INS5(b0,b1,b2,b3,b4, cB0); INS5(b0,b1,b2,b3,b4, cB1);
                INS5(c0,c1,c2,c3,c4, cC0); INS5(c0,c1,c2,c3,c4, cC1);
                INS5(d0,d1,d2,d3,d4, cD0); INS5(d0,d1,d2,d3,d4, cD1);
            }
            if (j < je) {
                float4 t = tile[j];
                INS5(a0,a1,a2,a3,a4, cdist(ax,ay,az,t));
                INS5(b0,b1,b2,b3,b4, cdist(bx,by,bz,t));
                INS5(c0,c1,c2,c3,c4, cdist(cx,cy,cz,t));
                INS5(d0,d1,d2,d3,d4, cdist(dx,dy,dz,t));
            }
        }
        __syncthreads();   // tile dead after this barrier on the last iter
    }

    // publish per-wave results into part (overlays tile — safe post-barrier)
    if (role < 2) {
        PART(w,   0+l, 0) = mA;
        PART(w,  64+l, 0) = mB;
        PART(w, 128+l, 0) = mC;
        PART(w, 192+l, 0) = mD;
    } else {
        PART(w,  0+l,0)=a0; PART(w,  0+l,1)=a1; PART(w,  0+l,2)=a2; PART(w,  0+l,3)=a3; PART(w,  0+l,4)=a4;
        PART(w, 64+l,0)=b0; PART(w, 64+l,1)=b1; PART(w, 64+l,2)=b2; PART(w, 64+l,3)=b3; PART(w, 64+l,4)=b4;
        PART(w,128+l,0)=c0; PART(w,128+l,1)=c1; PART(w,128+l,2)=c2; PART(w,128+l,3)=c3; PART(w,128+l,4)=c4;
        PART(w,192+l,0)=d0; PART(w,192+l,1)=d1; PART(w,192+l,2)=d2; PART(w,192+l,3)=d3; PART(w,192+l,4)=d4;
    }
    __syncthreads();

    // merge 4 waves -> per-(query,split) partial in ws. THREADS == QB.
    int t = threadIdx.x;
    int q = chunk * QB + t;
    if (q < N) {
        if (role < 2) {
            float best = fminf(fminf(PART(0,t,0), PART(1,t,0)),
                               fminf(PART(2,t,0), PART(3,t,0)));
            chamPart[(((size_t)role * B + b) * N + q) * CSPLIT + split] = best;
        } else {
            float s0=FLT_INF,s1=FLT_INF,s2=FLT_INF,s3=FLT_INF,s4=FLT_INF;
            #pragma unroll
            for (int ww = 0; ww < NWAVE; ++ww)
                #pragma unroll
                for (int k = 0; k < 5; ++k)
                    INS5(s0,s1,s2,s3,s4, PART(ww,t,k));
            float* kp = &knnPart[(((size_t)b * N + q) * KSPLIT + split) * 5];
            kp[0]=s0; kp[1]=s1; kp[2]=s2; kp[3]=s3; kp[4]=s4;
        }
    }
#undef PART
}

// merge partials -> cd loss (acc[0]) and uniform loss (acc[1])
__global__ __launch_bounds__(THREADS) void mergeB_kernel(
    const float* __restrict__ pred, const float* __restrict__ gt,
    const float* __restrict__ radius,
    const float* __restrict__ chamPart, const float* __restrict__ knnPart,
    float* __restrict__ acc, int B, int N)
{
    const float FLT_INF = 3.4e38f;
    const float RADIUS = 0.07f;
    const float INV_H2 = 1.0f / (0.03f * 0.03f);
    const float EPSV = 1e-12f;

    __shared__ float redc[NWAVE], redu[NWAVE];

    int gid = blockIdx.x * THREADS + threadIdx.x;
    int BN = B * N;
    float cd = 0.f, uni = 0.f;

    if (gid < 2 * BN) {
        int role = gid / BN, q = gid % BN, b = q / N;
        const float* qp = ((role == 0) ? gt : pred) + (size_t)q * 3;
        float x = qp[0], y = qp[1], z = qp[2];
        float na = fmaf(x,x,fmaf(y,y,z*z));
        const float* cp = &chamPart[(size_t)gid * CSPLIT];
        float m = cp[0];
        #pragma unroll
        for (int s = 1; s < CSPLIT; ++s) m = fminf(m, cp[s]);
        float wgt = (role == 0) ? 0.8f : 0.2f;
        cd = wgt * (na + m) / radius[b];
    } else if (gid < 3 * BN) {
        int q = gid - 2 * BN, b = q / N;
        const float* qp = pred + (size_t)q * 3;
        float x = qp[0], y = qp[1], z = qp[2];
        float na = fmaf(x,x,fmaf(y,y,z*z));
        const float* kp = &knnPart[(size_t)q * KSPLIT * 5];
        float s0=FLT_INF,s1=FLT_INF,s2=FLT_INF,s3=FLT_INF,s4=FLT_INF;
        #pragma unroll
        for (int k = 0; k < KSPLIT * 5; ++k) INS5(s0,s1,s2,s3,s4, kp[k]);
        // s0 == self (global min): dropped. ranks 1..4 = 4-NN.
        float ss[4] = {s1, s2, s3, s4};
        #pragma unroll
        for (int k = 0; k < 4; ++k) {
            float d2 = fmaxf(na + ss[k], EPSV);
            uni += (RADIUS - sqrtf(d2)) * __expf(-d2 * INV_H2);
        }
    }

    int w = threadIdx.x >> 6, l = threadIdx.x & 63;
    #pragma unroll
    for (int off = 32; off > 0; off >>= 1) {
        cd  += __shfl_down(cd, off, 64);
        uni += __shfl_down(uni, off, 64);
    }
    if (l == 0) { redc[w] = cd; redu[w] = uni; }
    __syncthreads();
    if (threadIdx.x == 0) {
        atomicAdd(&acc[0], redc[0]+redc[1]+redc[2]+redc[3]);
        atomicAdd(&acc[1], redu[0]+redu[1]+redu[2]+redu[3]);
    }
}

// ---------------- Fallback: proven monolithic kernel (small ws) ----------------
__device__ __forceinline__ float sdist(float qx,float qy,float qz,float4 t) {
    return fmaf(-2.f, fmaf(qx,t.x,fmaf(qy,t.y,qz*t.z)), t.w);
}
__global__ __launch_bounds__(THREADS) void mono_kernel(
    const float* __restrict__ pred, const float* __restrict__ gt,
    const float* __restrict__ radius, float* __restrict__ acc,
    int B, int N, int chunksPerBatch)
{
    __shared__ float4 tgt[2048];
    __shared__ float part[NWAVE][128][5];
    __shared__ float naArr[128];
    __shared__ float red[NWAVE];
    const float FLT_INF = 3.4e38f;
    const float RADIUS = 0.07f;
    const float INV_H2 = 1.0f / (0.03f * 0.03f);
    const float EPSV = 1e-12f;

    int blocksPerRole = B * chunksPerBatch;
    int role  = blockIdx.x / blocksPerRole;
    int rem   = blockIdx.x % blocksPerRole;
    int b     = rem / chunksPerBatch;
    int chunk = rem % chunksPerBatch;
    int w = threadIdx.x >> 6, l = threadIdx.x & 63;
    int qi0 = chunk * 128 + l, qi1 = qi0 + 64;
    const float* qb = (((role == 0) ? gt : pred)) + (size_t)b * N * 3;
    const float* tb = (((role == 1) ? gt : pred)) + (size_t)b * N * 3;
    float q0x=0,q0y=0,q0z=0,q1x=0,q1y=0,q1z=0;
    if (qi0 < N) { q0x=qb[qi0*3]; q0y=qb[qi0*3+1]; q0z=qb[qi0*3+2]; }
    if (qi1 < N) { q1x=qb[qi1*3]; q1y=qb[qi1*3+1]; q1z=qb[qi1*3+2]; }
    float na0 = fmaf(q0x,q0x,fmaf(q0y,q0y,q0z*q0z));
    float na1 = fmaf(q1x,q1x,fmaf(q1y,q1y,q1z*q1z));
    if (w == 0) { naArr[l] = na0; naArr[l+64] = na1; }
    float mA=FLT_INF,mB=FLT_INF;
    float e0=FLT_INF,e1=FLT_INF,e2=FLT_INF,e3=FLT_INF,e4=FLT_INF;
    float o0=FLT_INF,o1=FLT_INF,o2=FLT_INF,o3=FLT_INF,o4=FLT_INF;
    for (int t0 = 0; t0 < N; t0 += 2048) {
        int cnt = min(2048, N - t0);
        for (int k = threadIdx.x; k < cnt; k += THREADS) {
            float x = tb[(size_t)(t0+k)*3], y = tb[(size_t)(t0+k)*3+1], z = tb[(size_t)(t0+k)*3+2];
            tgt[k] = make_float4(x,y,z,fmaf(x,x,fmaf(y,y,z*z)));
        }
        __syncthreads();
        int segsz = (cnt + NWAVE - 1)/NWAVE;
        int jb = w*segsz, je = min(jb+segsz, cnt);
        if (role < 2) {
            for (int j = jb; j < je; ++j) {
                float4 t = tgt[j];
                mA = fminf(mA, sdist(q0x,q0y,q0z,t));
                mB = fminf(mB, sdist(q1x,q1y,q1z,t));
            }
        } else {
            for (int j = jb; j < je; ++j) {
                float4 t = tgt[j];
                INS5(e0,e1,e2,e3,e4, sdist(q0x,q0y,q0z,t));
                INS5(o0,o1,o2,o3,o4, sdist(q1x,q1y,q1z,t));
            }
        }
        __syncthreads();
    }
    if (role < 2) { part[w][l][0]=mA; part[w][l+64][0]=mB; }
    else {
        part[w][l][0]=e0; part[w][l][1]=e1; part[w][l][2]=e2; part[w][l][3]=e3; part[w][l][4]=e4;
        part[w][l+64][0]=o0; part[w][l+64][1]=o1; part[w][l+64][2]=o2; part[w][l+64][3]=o3; part[w][l+64][4]=o4;
    }
    __syncthreads();
    float contrib = 0.f;
    int t = threadIdx.x;
    if (t < 128) {
        int q = chunk*128 + t;
        if (q < N) {
            float inv_r = 1.0f / radius[b];
            float na = naArr[t];
            if (role < 2) {
                float best = fminf(fminf(part[0][t][0],part[1][t][0]),
                                   fminf(part[2][t][0],part[3][t][0]));
                contrib = ((role==0)?0.8f:0.2f) * inv_r * (na + best);
            } else {
                float s0=FLT_INF,s1=FLT_INF,s2=FLT_INF,s3=FLT_INF,s4=FLT_INF;
                #pragma unroll
                for (int ww = 0; ww < NWAVE; ++ww)
                    #pragma unroll
                    for (int k = 0; k < 5; ++k)
                        INS5(s0,s1,s2,s3,s4, part[ww][t][k]);
                float ss[4] = {s1,s2,s3,s4};
                float s = 0.f;
                #pragma unroll
                for (int k = 0; k < 4; ++k) {
                    float d2 = fmaxf(na + ss[k], EPSV);
                    s += (RADIUS - sqrtf(d2)) * __expf(-d2 * INV_H2);
                }
                contrib = s;
            }
        }
    }
    #pragma unroll
    for (int off = 32; off > 0; off >>= 1) contrib += __shfl_down(contrib, off, 64);
    if (l == 0) red[w] = contrib;
    __syncthreads();
    if (threadIdx.x == 0)
        atomicAdd(&acc[role < 2 ? 0 : 1], red[0]+red[1]+red[2]+red[3]);
}

__global__ void upsample_final_kernel(const float* __restrict__ acc,
                                      float* __restrict__ out,
                                      float invCd, float invUni)
{
    out[0] = fmaf(acc[0], invCd, 0.1f * acc[1] * invUni);
}

extern "C" void kernel_launch(void* const* d_in, const int* in_sizes, int n_in,
                              void* d_out, int out_size, void* d_ws, size_t ws_size,
                              hipStream_t stream) {
    const float* pred   = (const float*)d_in[0];
    const float* gt     = (const float*)d_in[1];
    const float* radius = (const float*)d_in[2];
    float* out = (float*)d_out;
    float* acc = (float*)d_ws;

    int B = in_sizes[2];
    int N = in_sizes[0] / (3 * B);
    size_t BN = (size_t)B * N;

    hipMemsetAsync(acc, 0, 2 * sizeof(float), stream);

    size_t chamBytes = 2 * BN * CSPLIT * sizeof(float);
    size_t knnBytes  = BN * KSPLIT * 5 * sizeof(float);
    size_t need = 64 + chamBytes + knnBytes;

    if (ws_size >= need && (N % QB) == 0) {
        float* chamPart = (float*)((char*)d_ws + 64);
        float* knnPart  = chamPart + 2 * BN * CSPLIT;
        int chunks = N / QB;
        int knnItems  = B * chunks * KSPLIT;
        int chamItems = 2 * B * chunks * CSPLIT;
        scan_kernel<<<knnItems + chamItems, THREADS, 0, stream>>>(
            pred, gt, chamPart, knnPart, B, N, chunks, knnItems);
        int mb = (int)((3 * BN + THREADS - 1) / THREADS);
        mergeB_kernel<<<mb, THREADS, 0, stream>>>(pred, gt, radius,
                                                  chamPart, knnPart, acc, B, N);
    } else {
        int chunksPerBatch = (N + 127) / 128;
        int blocks = 3 * B * chunksPerBatch;
        mono_kernel<<<blocks, THREADS, 0, stream>>>(pred, gt, radius, acc,
                                                    B, N, chunksPerBatch);
    }

    float invCd  = 1.0f / ((float)B * (float)N);
    float invUni = 1.0f / ((float)B * (float)N * 4.0f);
    upsample_final_kernel<<<1, 1, 0, stream>>>(acc, out, invCd, invUni);
}

// Round 14
// 69.779 us; speedup vs baseline: 1.1008x; 1.1008x over previous
//
#include <hip/hip_runtime.h>
#include <math.h>

#define THREADS 256
#define NWAVE 4
#define QB 256           // queries per block (4 per lane)
#define TILE 512         // targets per LDS tile (8 KB)
#define KSPLIT 4         // knn target split factor
#define CSPLIT 2         // chamfer target split factor

#define MED3 __builtin_amdgcn_fmed3f

// branchless sorted insert via med3: 5 independent ops, no serial chain.
#define INS5(L0,L1,L2,L3,L4,C) do { float c_=(C);              \
    float n0_=fminf(L0,c_);                                    \
    float n1_=MED3(L0,L1,c_);                                  \
    float n2_=MED3(L1,L2,c_);                                  \
    float n3_=MED3(L2,L3,c_);                                  \
    float n4_=MED3(L3,L4,c_);                                  \
    L0=n0_; L1=n1_; L2=n2_; L3=n3_; L4=n4_; } while (0)

// tile stores (-2x, -2y, -2z, |t|^2): dist-na = 3 fma
__device__ __forceinline__ float cdist(float qx,float qy,float qz,float4 t) {
    return fmaf(qx, t.x, fmaf(qy, t.y, fmaf(qz, t.z, t.w)));
}

// blocks [0, knnItems): role 2 (knn), targets split KSPLIT ways -> knnPart
// blocks [knnItems,...): roles 0/1 (chamfer), targets split CSPLIT ways -> chamPart
__global__ __launch_bounds__(THREADS) void scan_kernel(
    const float* __restrict__ pred, const float* __restrict__ gt,
    float* __restrict__ chamPart, float* __restrict__ knnPart,
    int B, int N, int chunks, int knnItems)
{
    // LDS union: tile (512 float4 = 2048 floats) overlays part
    // (NWAVE*QB*5 = 5120 floats). tile is dead after the loop's final barrier.
    __shared__ float shbuf[NWAVE * QB * 5];
    float4* tile = reinterpret_cast<float4*>(shbuf);
#define PART(ww,t,k) shbuf[(((ww) * QB) + (t)) * 5 + (k)]

    const float FLT_INF = 3.4e38f;
    int w = threadIdx.x >> 6, l = threadIdx.x & 63;

    int role, b, chunk, split, tBegin, tEnd;
    if ((int)blockIdx.x < knnItems) {
        role = 2;
        int u = blockIdx.x;
        split = u % KSPLIT; u /= KSPLIT;
        chunk = u % chunks; b = u / chunks;
        int seg = (N + KSPLIT - 1) / KSPLIT;
        tBegin = split * seg; tEnd = min(tBegin + seg, N);
    } else {
        int u = blockIdx.x - knnItems;
        int perRole = B * chunks * CSPLIT;
        role = u / perRole; u %= perRole;
        split = u % CSPLIT; u /= CSPLIT;
        chunk = u % chunks; b = u / chunks;
        int seg = (N + CSPLIT - 1) / CSPLIT;
        tBegin = split * seg; tEnd = min(tBegin + seg, N);
    }

    const float* qb = (((role == 0) ? gt : pred)) + (size_t)b * N * 3;
    const float* tb = (((role == 1) ? gt : pred)) + (size_t)b * N * 3;

    // 4 queries per lane, slots s*64 + l
    int qiA = chunk * QB +   0 + l;
    int qiB = chunk * QB +  64 + l;
    int qiC = chunk * QB + 128 + l;
    int qiD = chunk * QB + 192 + l;

    float ax=0.f,ay=0.f,az=0.f, bx=0.f,by=0.f,bz=0.f;
    float cx=0.f,cy=0.f,cz=0.f, dx=0.f,dy=0.f,dz=0.f;
    if (qiA < N) { ax=qb[qiA*3]; ay=qb[qiA*3+1]; az=qb[qiA*3+2]; }
    if (qiB < N) { bx=qb[qiB*3]; by=qb[qiB*3+1]; bz=qb[qiB*3+2]; }
    if (qiC < N) { cx=qb[qiC*3]; cy=qb[qiC*3+1]; cz=qb[qiC*3+2]; }
    if (qiD < N) { dx=qb[qiD*3]; dy=qb[qiD*3+1]; dz=qb[qiD*3+2]; }

    // chamfer mins (1 chain per query)
    float mA = FLT_INF, mB = FLT_INF, mC = FLT_INF, mD = FLT_INF;
    // knn top-5 lists per query
    float a0=FLT_INF,a1=FLT_INF,a2=FLT_INF,a3=FLT_INF,a4=FLT_INF;
    float b0=FLT_INF,b1=FLT_INF,b2=FLT_INF,b3=FLT_INF,b4=FLT_INF;
    float c0=FLT_INF,c1=FLT_INF,c2=FLT_INF,c3=FLT_INF,c4=FLT_INF;
    float d0=FLT_INF,d1=FLT_INF,d2=FLT_INF,d3=FLT_INF,d4=FLT_INF;

    for (int t0 = tBegin; t0 < tEnd; t0 += TILE) {
        int cnt = min(TILE, tEnd - t0);
        for (int k = threadIdx.x; k < cnt; k += THREADS) {
            float x = tb[(size_t)(t0 + k) * 3 + 0];
            float y = tb[(size_t)(t0 + k) * 3 + 1];
            float z = tb[(size_t)(t0 + k) * 3 + 2];
            tile[k] = make_float4(-2.f*x, -2.f*y, -2.f*z, fmaf(x,x,fmaf(y,y,z*z)));
        }
        __syncthreads();

        int seg = (cnt + NWAVE - 1) / NWAVE;
        int jb = w * seg, je = min(jb + seg, cnt);

        if (role < 2) {
            int j = jb;
            for (; j + 2 <= je; j += 2) {
                float4 t0v = tile[j], t1v = tile[j+1];
                float cA0 = cdist(ax,ay,az,t0v), cA1 = cdist(ax,ay,az,t1v);
                float cB0 = cdist(bx,by,bz,t0v), cB1 = cdist(bx,by,bz,t1v);
                float cC0 = cdist(cx,cy,cz,t0v), cC1 = cdist(cx,cy,cz,t1v);
                float cD0 = cdist(dx,dy,dz,t0v), cD1 = cdist(dx,dy,dz,t1v);
                mA = fminf(fminf(mA, cA0), cA1);      // nested -> v_min3
                mB = fminf(fminf(mB, cB0), cB1);
                mC = fminf(fminf(mC, cC0), cC1);
                mD = fminf(fminf(mD, cD0), cD1);
            }
            if (j < je) {
                float4 t = tile[j];
                mA = fminf(mA, cdist(ax,ay,az,t));
                mB = fminf(mB, cdist(bx,by,bz,t));
                mC = fminf(mC, cdist(cx,cy,cz,t));
                mD = fminf(mD, cdist(dx,dy,dz,t));
            }
        } else {
            int j = jb;
            for (; j + 2 <= je; j += 2) {
                float4 t0v = tile[j], t1v = tile[j+1];
                float cA0 = cdist(ax,ay,az,t0v), cA1 = cdist(ax,ay,az,t1v);
                float cB0 = cdist(bx,by,bz,t0v), cB1 = cdist(bx,by,bz,t1v);
                float cC0 = cdist(cx,cy,cz,t0v), cC1 = cdist(cx,cy,cz,t1v);
                float cD0 = cdist(dx,dy,dz,t0v), cD1 = cdist(dx,dy,dz,t1v);
                INS5(a0,a1,a2,a3,a4, cA0); INS5(a0,a1,a2,a3,a4, cA1);
                INS5(b0,b1,b2,b3,b4, cB0); INS5(b0,b1,b2,b3,b4, cB1);
                INS5(c0,c1,c2,c3,c4, cC0); INS5(c0,c1,c2,c3,c4, cC1);
                INS5(d0,d1,d2,d3,d4, cD0); INS5(d0,d1,d2,d3,d4, cD1);
            }
            if (j < je) {
                float4 t = tile[j];
                INS5(a0,a1,a2,a3,a4, cdist(ax,ay,az,t));
                INS5(b0,b1,b2,b3,b4, cdist(bx,by,bz,t));
                INS5(c0,c1,c2,c3,c4, cdist(cx,cy,cz,t));
                INS5(d0,d1,d2,d3,d4, cdist(dx,dy,dz,t));
            }
        }
        __syncthreads();   // tile dead after this barrier on the last iter
    }

    // publish per-wave results into part (overlays tile — safe post-barrier)
    if (role < 2) {
        PART(w,   0+l, 0) = mA;
        PART(w,  64+l, 0) = mB;
        PART(w, 128+l, 0) = mC;
        PART(w, 192+l, 0) = mD;
    } else {
        PART(w,  0+l,0)=a0; PART(w,  0+l,1)=a1; PART(w,  0+l,2)=a2; PART(w,  0+l,3)=a3; PART(w,  0+l,4)=a4;
        PART(w, 64+l,0)=b0; PART(w, 64+l,1)=b1; PART(w, 64+l,2)=b2; PART(w, 64+l,3)=b3; PART(w, 64+l,4)=b4;
        PART(w,128+l,0)=c0; PART(w,128+l,1)=c1; PART(w,128+l,2)=c2; PART(w,128+l,3)=c3; PART(w,128+l,4)=c4;
        PART(w,192+l,0)=d0; PART(w,192+l,1)=d1; PART(w,192+l,2)=d2; PART(w,192+l,3)=d3; PART(w,192+l,4)=d4;
    }
    __syncthreads();

    // merge 4 waves -> per-(query,split) partial in ws. THREADS == QB.
    int t = threadIdx.x;
    int q = chunk * QB + t;
    if (q < N) {
        if (role < 2) {
            float best = fminf(fminf(PART(0,t,0), PART(1,t,0)),
                               fminf(PART(2,t,0), PART(3,t,0)));
            chamPart[(((size_t)role * B + b) * N + q) * CSPLIT + split] = best;
        } else {
            float s0=FLT_INF,s1=FLT_INF,s2=FLT_INF,s3=FLT_INF,s4=FLT_INF;
            #pragma unroll
            for (int ww = 0; ww < NWAVE; ++ww)
                #pragma unroll
                for (int k = 0; k < 5; ++k)
                    INS5(s0,s1,s2,s3,s4, PART(ww,t,k));
            float* kp = &knnPart[(((size_t)b * N + q) * KSPLIT + split) * 5];
            kp[0]=s0; kp[1]=s1; kp[2]=s2; kp[3]=s3; kp[4]=s4;
        }
    }
#undef PART
}

// fused merge: one thread per query handles role-0 cham + role-1 cham + knn
__global__ __launch_bounds__(THREADS) void mergeB_kernel(
    const float* __restrict__ pred, const float* __restrict__ gt,
    const float* __restrict__ radius,
    const float* __restrict__ chamPart, const float* __restrict__ knnPart,
    float* __restrict__ acc, int B, int N)
{
    const float FLT_INF = 3.4e38f;
    const float RADIUS = 0.07f;
    const float INV_H2 = 1.0f / (0.03f * 0.03f);
    const float EPSV = 1e-12f;

    __shared__ float redc[NWAVE], redu[NWAVE];

    int q = blockIdx.x * THREADS + threadIdx.x;
    int BN = B * N;
    float cd = 0.f, uni = 0.f;

    if (q < BN) {
        int b = q / N;
        float inv_r = 1.0f / radius[b];

        // role 0: gt query vs pred targets
        {
            const float* qp = gt + (size_t)q * 3;
            float x = qp[0], y = qp[1], z = qp[2];
            float na = fmaf(x,x,fmaf(y,y,z*z));
            const float* cp = &chamPart[(size_t)q * CSPLIT];
            float m = cp[0];
            #pragma unroll
            for (int s = 1; s < CSPLIT; ++s) m = fminf(m, cp[s]);
            cd = 0.8f * (na + m) * inv_r;
        }
        // role 1 + knn: pred query
        {
            const float* qp = pred + (size_t)q * 3;
            float x = qp[0], y = qp[1], z = qp[2];
            float na = fmaf(x,x,fmaf(y,y,z*z));
            const float* cp = &chamPart[((size_t)BN + q) * CSPLIT];
            float m = cp[0];
            #pragma unroll
            for (int s = 1; s < CSPLIT; ++s) m = fminf(m, cp[s]);
            cd += 0.2f * (na + m) * inv_r;

            const float* kp = &knnPart[(size_t)q * KSPLIT * 5];
            float s0=FLT_INF,s1=FLT_INF,s2=FLT_INF,s3=FLT_INF,s4=FLT_INF;
            #pragma unroll
            for (int k = 0; k < KSPLIT * 5; ++k) INS5(s0,s1,s2,s3,s4, kp[k]);
            // s0 == self (global min): dropped. ranks 1..4 = 4-NN.
            float ss[4] = {s1, s2, s3, s4};
            #pragma unroll
            for (int k = 0; k < 4; ++k) {
                float d2 = fmaxf(na + ss[k], EPSV);
                uni += (RADIUS - sqrtf(d2)) * __expf(-d2 * INV_H2);
            }
        }
    }

    int w = threadIdx.x >> 6, l = threadIdx.x & 63;
    #pragma unroll
    for (int off = 32; off > 0; off >>= 1) {
        cd  += __shfl_down(cd, off, 64);
        uni += __shfl_down(uni, off, 64);
    }
    if (l == 0) { redc[w] = cd; redu[w] = uni; }
    __syncthreads();
    if (threadIdx.x == 0) {
        atomicAdd(&acc[0], redc[0]+redc[1]+redc[2]+redc[3]);
        atomicAdd(&acc[1], redu[0]+redu[1]+redu[2]+redu[3]);
    }
}

// ---------------- Fallback: proven monolithic kernel (small ws) ----------------
__device__ __forceinline__ float sdist(float qx,float qy,float qz,float4 t) {
    return fmaf(-2.f, fmaf(qx,t.x,fmaf(qy,t.y,qz*t.z)), t.w);
}
__global__ __launch_bounds__(THREADS) void mono_kernel(
    const float* __restrict__ pred, const float* __restrict__ gt,
    const float* __restrict__ radius, float* __restrict__ acc,
    int B, int N, int chunksPerBatch)
{
    __shared__ float4 tgt[2048];
    __shared__ float part[NWAVE][128][5];
    __shared__ float naArr[128];
    __shared__ float red[NWAVE];
    const float FLT_INF = 3.4e38f;
    const float RADIUS = 0.07f;
    const float INV_H2 = 1.0f / (0.03f * 0.03f);
    const float EPSV = 1e-12f;

    int blocksPerRole = B * chunksPerBatch;
    int role  = blockIdx.x / blocksPerRole;
    int rem   = blockIdx.x % blocksPerRole;
    int b     = rem / chunksPerBatch;
    int chunk = rem % chunksPerBatch;
    int w = threadIdx.x >> 6, l = threadIdx.x & 63;
    int qi0 = chunk * 128 + l, qi1 = qi0 + 64;
    const float* qb = (((role == 0) ? gt : pred)) + (size_t)b * N * 3;
    const float* tb = (((role == 1) ? gt : pred)) + (size_t)b * N * 3;
    float q0x=0,q0y=0,q0z=0,q1x=0,q1y=0,q1z=0;
    if (qi0 < N) { q0x=qb[qi0*3]; q0y=qb[qi0*3+1]; q0z=qb[qi0*3+2]; }
    if (qi1 < N) { q1x=qb[qi1*3]; q1y=qb[qi1*3+1]; q1z=qb[qi1*3+2]; }
    float na0 = fmaf(q0x,q0x,fmaf(q0y,q0y,q0z*q0z));
    float na1 = fmaf(q1x,q1x,fmaf(q1y,q1y,q1z*q1z));
    if (w == 0) { naArr[l] = na0; naArr[l+64] = na1; }
    float mA=FLT_INF,mB=FLT_INF;
    float e0=FLT_INF,e1=FLT_INF,e2=FLT_INF,e3=FLT_INF,e4=FLT_INF;
    float o0=FLT_INF,o1=FLT_INF,o2=FLT_INF,o3=FLT_INF,o4=FLT_INF;
    for (int t0 = 0; t0 < N; t0 += 2048) {
        int cnt = min(2048, N - t0);
        for (int k = threadIdx.x; k < cnt; k += THREADS) {
            float x = tb[(size_t)(t0+k)*3], y = tb[(size_t)(t0+k)*3+1], z = tb[(size_t)(t0+k)*3+2];
            tgt[k] = make_float4(x,y,z,fmaf(x,x,fmaf(y,y,z*z)));
        }
        __syncthreads();
        int segsz = (cnt + NWAVE - 1)/NWAVE;
        int jb = w*segsz, je = min(jb+segsz, cnt);
        if (role < 2) {
            for (int j = jb; j < je; ++j) {
                float4 t = tgt[j];
                mA = fminf(mA, sdist(q0x,q0y,q0z,t));
                mB = fminf(mB, sdist(q1x,q1y,q1z,t));
            }
        } else {
            for (int j = jb; j < je; ++j) {
                float4 t = tgt[j];
                INS5(e0,e1,e2,e3,e4, sdist(q0x,q0y,q0z,t));
                INS5(o0,o1,o2,o3,o4, sdist(q1x,q1y,q1z,t));
            }
        }
        __syncthreads();
    }
    if (role < 2) { part[w][l][0]=mA; part[w][l+64][0]=mB; }
    else {
        part[w][l][0]=e0; part[w][l][1]=e1; part[w][l][2]=e2; part[w][l][3]=e3; part[w][l][4]=e4;
        part[w][l+64][0]=o0; part[w][l+64][1]=o1; part[w][l+64][2]=o2; part[w][l+64][3]=o3; part[w][l+64][4]=o4;
    }
    __syncthreads();
    float contrib = 0.f;
    int t = threadIdx.x;
    if (t < 128) {
        int q = chunk*128 + t;
        if (q < N) {
            float inv_r = 1.0f / radius[b];
            float na = naArr[t];
            if (role < 2) {
                float best = fminf(fminf(part[0][t][0],part[1][t][0]),
                                   fminf(part[2][t][0],part[3][t][0]));
                contrib = ((role==0)?0.8f:0.2f) * inv_r * (na + best);
            } else {
                float s0=FLT_INF,s1=FLT_INF,s2=FLT_INF,s3=FLT_INF,s4=FLT_INF;
                #pragma unroll
                for (int ww = 0; ww < NWAVE; ++ww)
                    #pragma unroll
                    for (int k = 0; k < 5; ++k)
                        INS5(s0,s1,s2,s3,s4, part[ww][t][k]);
                float ss[4] = {s1,s2,s3,s4};
                float s = 0.f;
                #pragma unroll
                for (int k = 0; k < 4; ++k) {
                    float d2 = fmaxf(na + ss[k], EPSV);
                    s += (RADIUS - sqrtf(d2)) * __expf(-d2 * INV_H2);
                }
                contrib = s;
            }
        }
    }
    #pragma unroll
    for (int off = 32; off > 0; off >>= 1) contrib += __shfl_down(contrib, off, 64);
    if (l == 0) red[w] = contrib;
    __syncthreads();
    if (threadIdx.x == 0)
        atomicAdd(&acc[role < 2 ? 0 : 1], red[0]+red[1]+red[2]+red[3]);
}

__global__ void upsample_final_kernel(const float* __restrict__ acc,
                                      float* __restrict__ out,
                                      float invCd, float invUni)
{
    out[0] = fmaf(acc[0], invCd, 0.1f * acc[1] * invUni);
}

extern "C" void kernel_launch(void* const* d_in, const int* in_sizes, int n_in,
                              void* d_out, int out_size, void* d_ws, size_t ws_size,
                              hipStream_t stream) {
    const float* pred   = (const float*)d_in[0];
    const float* gt     = (const float*)d_in[1];
    const float* radius = (const float*)d_in[2];
    float* out = (float*)d_out;
    float* acc = (float*)d_ws;

    int B = in_sizes[2];
    int N = in_sizes[0] / (3 * B);
    size_t BN = (size_t)B * N;

    hipMemsetAsync(acc, 0, 2 * sizeof(float), stream);

    size_t chamBytes = 2 * BN * CSPLIT * sizeof(float);
    size_t knnBytes  = BN * KSPLIT * 5 * sizeof(float);
    size_t need = 64 + chamBytes + knnBytes;

    if (ws_size >= need && (N % QB) == 0) {
        float* chamPart = (float*)((char*)d_ws + 64);
        float* knnPart  = chamPart + 2 * BN * CSPLIT;
        int chunks = N / QB;
        int knnItems  = B * chunks * KSPLIT;
        int chamItems = 2 * B * chunks * CSPLIT;
        scan_kernel<<<knnItems + chamItems, THREADS, 0, stream>>>(
            pred, gt, chamPart, knnPart, B, N, chunks, knnItems);
        int mb = (int)((BN + THREADS - 1) / THREADS);
        mergeB_kernel<<<mb, THREADS, 0, stream>>>(pred, gt, radius,
                                                  chamPart, knnPart, acc, B, N);
    } else {
        int chunksPerBatch = (N + 127) / 128;
        int blocks = 3 * B * chunksPerBatch;
        mono_kernel<<<blocks, THREADS, 0, stream>>>(pred, gt, radius, acc,
                                                    B, N, chunksPerBatch);
    }

    float invCd  = 1.0f / ((float)B * (float)N);
    float invUni = 1.0f / ((float)B * (float)N * 4.0f);
    upsample_final_kernel<<<1, 1, 0, stream>>>(acc, out, invCd, invUni);
}